// Round 10
// baseline (326.796 us; speedup 1.0000x reference)
//
#include <hip/hip_runtime.h>
#include <hip/hip_cooperative_groups.h>
#include <stdint.h>

namespace cg = cooperative_groups;

#define HW       262144u     // 512*512
#define NPIX     1048576u    // 4*HW (pixel index fits in 20 bits)
#define NSEL     2048u       // POS_NUM*B = NEG_NUM*B
#define NSEG     1024u       // one segment per pixel-tile per list
#define SEGCAP   16u         // slots/segment (keep-prob 1/32 -> mean ~2.65)
#define DENSECAP 3584u       // LDS gather capacity (mean ~2715, +16 sigma)
#define CGRID    512u        // cooperative grid: 2 tiles/block -> big co-residency slack

// workspace byte offsets (~450 KB total)
#define OFF_SEG     0u        // u64[2][NSEG][SEGCAP] = 256 KB (zero-filled unused slots)
#define OFF_IDX     262144u   // u32[4096] pos then neg
#define OFF_VA      278528u   // f32[4096*5]
#define OFF_WA      360448u   // f32[4096*5]
#define OFF_PSUM    442368u   // f32[1024]
#define OFF_PNNZ    446464u   // u32[1024]

// ---------------- Threefry-2x32-20 (JAX partitionable PRNG) ----------------
#define TF_ROUND(r) { x0 += x1; x1 = (x1 << (r)) | (x1 >> (32 - (r))); x1 ^= x0; }
__host__ __device__ inline void threefry2x32_(uint32_t k0, uint32_t k1,
                                              uint32_t& x0, uint32_t& x1) {
  uint32_t k2 = k0 ^ k1 ^ 0x1BD11BDAu;
  x0 += k0; x1 += k1;
  TF_ROUND(13) TF_ROUND(15) TF_ROUND(26) TF_ROUND(6)
  x0 += k1; x1 += k2 + 1u;
  TF_ROUND(17) TF_ROUND(29) TF_ROUND(16) TF_ROUND(24)
  x0 += k2; x1 += k0 + 2u;
  TF_ROUND(13) TF_ROUND(15) TF_ROUND(26) TF_ROUND(6)
  x0 += k0; x1 += k1 + 3u;
  TF_ROUND(17) TF_ROUND(29) TF_ROUND(16) TF_ROUND(24)
  x0 += k1; x1 += k2 + 4u;
  TF_ROUND(13) TF_ROUND(15) TF_ROUND(26) TF_ROUND(6)
  x0 += k2; x1 += k0 + 5u;
}

// ---------------- shared-memory overlay (phases are sync-separated) ----------
struct SelS {
  uint64_t dense[DENSECAP];   // 28672 B
  uint64_t spref;
  uint32_t hist[2048];        // 8192 B
  uint32_t part[256];         // 1024 B
  uint32_t skk, rank, ntot;
  int gsel;
};
struct ProjS {
  float sG[25];
  float sGw[4][25];
};
struct PairS {
  float sv[640], sw[640];
  float rs[256];
  uint32_t rn[256];
};
union SMemU {                 // sizeof ~= 37936 -> >=4 blocks/CU by LDS
  uint32_t cnt2[2];
  SelS sel;
  ProjS proj;
  PairS pair;
};

// =============== device phase bodies (shared by fused + fallback) ============

__device__ inline void front_body(uint32_t tile, int t, SMemU& sm,
    const float* __restrict__ pfegc, const float* __restrict__ ppre,
    const float* __restrict__ gt,
    uint32_t kp0, uint32_t kp1, uint32_t kn0, uint32_t kn1,
    uint64_t* __restrict__ seg) {
  __syncthreads();                          // guard LDS reuse on repeated calls
  if (t < 2) sm.cnt2[t] = 0;
  if (t < 2 * (int)SEGCAP) {                // zero-fill this tile's two segments
    uint32_t list = (uint32_t)t / SEGCAP, slot = (uint32_t)t % SEGCAP;
    seg[((size_t)list * NSEG + tile) * SEGCAP + slot] = 0ull;
  }
  __syncthreads();
  uint32_t base = tile * 1024u + (uint32_t)t * 4u;
  float4 pf = *(const float4*)(pfegc + base);
  float pfa[4] = { pf.x, pf.y, pf.z, pf.w };
  bool any = (pf.x >= 0.5f) || (pf.y >= 0.5f) || (pf.z >= 0.5f) || (pf.w >= 0.5f);
  if (any) {
    uint32_t hw = base & (HW - 1u);
    uint32_t bb = base >> 18;                 // base..base+3 share the image
    const float* pp = ppre + (size_t)bb * 3u * HW + hw;
    float4 p0 = *(const float4*)pp;
    float4 p1 = *(const float4*)(pp + HW);
    float4 p2 = *(const float4*)(pp + 2u * HW);
    float4 g4 = *(const float4*)(gt + base);
    float p0a[4] = { p0.x, p0.y, p0.z, p0.w };
    float p1a[4] = { p1.x, p1.y, p1.z, p1.w };
    float p2a[4] = { p2.x, p2.y, p2.z, p2.w };
    float ga[4]  = { g4.x, g4.y, g4.z, g4.w };
    #pragma unroll
    for (int j = 0; j < 4; ++j) {
      if (pfa[j] >= 0.5f && p0a[j] >= p1a[j] && p0a[j] >= p2a[j]) {
        uint32_t i = base + (uint32_t)j;
        bool gfg = ga[j] > 0.5f;
        uint32_t x0 = 0u, x1 = i;
        threefry2x32_(gfg ? kp0 : kn0, gfg ? kp1 : kn1, x0, x1);
        uint32_t r23 = (x0 ^ x1) >> 9;
        if ((r23 >> 18) == 0x1Fu) {           // fixed prefilter, keep-prob 1/32
          uint32_t list = gfg ? 0u : 1u;
          uint32_t r = atomicAdd(&sm.cnt2[list], 1u);  // u32 LDS atomic, rare
          if (r < SEGCAP)
            seg[((size_t)list * NSEG + tile) * SEGCAP + r] =
                (1ull << 43) | ((uint64_t)r23 << 20) | (uint64_t)(0xFFFFFu ^ i);
        }
      }
    }
  }
}

__device__ inline void sel_body(int list, int t, SMemU& sm,
    const uint64_t* __restrict__ seg, uint32_t* __restrict__ idxbuf) {
  uint32_t lane = (uint32_t)t & 63u;
  if (t == 0) { sm.sel.spref = 0ull; sm.sel.skk = NSEL; sm.sel.rank = 0; }
  const uint4* sp4 = (const uint4*)(seg + (size_t)list * NSEG * SEGCAP);
  // ---- Phase A: count valid keys (bit43 marker); 16B coalesced loads ----
  uint32_t c = 0;
  #pragma unroll 8
  for (int it = 0; it < 32; ++it) {
    uint4 v = sp4[(uint32_t)it * 256u + (uint32_t)t];
    c += ((v.y >> 11) & 1u) + ((v.w >> 11) & 1u);   // bit43 = bit11 of high word
  }
  sm.sel.part[t] = c;
  __syncthreads();
  for (int off = 1; off < 256; off <<= 1) {
    uint32_t x = sm.sel.part[t];
    uint32_t add = (t >= off) ? sm.sel.part[t - off] : 0u;
    __syncthreads();
    sm.sel.part[t] = x + add;
    __syncthreads();
  }
  uint32_t wbase = sm.sel.part[t] - c;      // exclusive prefix = thread's base
  if (t == 255) sm.sel.ntot = sm.sel.part[255];
  // ---- Phase B: re-load (L2-hot) and scatter to dense ----
  #pragma unroll 8
  for (int it = 0; it < 32; ++it) {
    uint4 v = sp4[(uint32_t)it * 256u + (uint32_t)t];
    uint64_t k0 = ((uint64_t)v.y << 32) | v.x;
    uint64_t k1 = ((uint64_t)v.w << 32) | v.z;
    if (k0 >> 43) { if (wbase < DENSECAP) sm.sel.dense[wbase] = k0; ++wbase; }
    if (k1 >> 43) { if (wbase < DENSECAP) sm.sel.dense[wbase] = k1; ++wbase; }
  }
  __syncthreads();
  uint32_t n = sm.sel.ntot; if (n > DENSECAP) n = DENSECAP;
  // ---- 4-round 11-bit radix select of the exact 2048th-largest key ----
  for (int r = 0; r < 4; ++r) {
    #pragma unroll
    for (int e = 0; e < 8; ++e) sm.sel.hist[t * 8 + e] = 0;
    __syncthreads();
    int csp = 44 - 11 * r;
    int cs = csp - 11;
    uint64_t pref = sm.sel.spref;
    for (uint32_t j = t; j < n; j += 256) {
      uint64_t key = sm.sel.dense[j];
      if ((key >> csp) == pref)
        atomicAdd(&sm.sel.hist[(uint32_t)(key >> cs) & 0x7FFu], 1u);
    }
    __syncthreads();
    uint32_t ss = 0;
    #pragma unroll
    for (int e = 0; e < 8; ++e) ss += sm.sel.hist[t * 8 + e];
    sm.sel.part[t] = ss;
    __syncthreads();
    for (int off = 1; off < 256; off <<= 1) {
      uint32_t x = sm.sel.part[t];
      uint32_t y = (t + off < 256) ? sm.sel.part[t + off] : 0u;
      __syncthreads();
      sm.sel.part[t] = x + y;
      __syncthreads();
    }
    uint32_t k = sm.sel.skk;
    if (sm.sel.part[t] >= k && (t == 255 || sm.sel.part[t + 1] < k)) sm.sel.gsel = t;
    __syncthreads();
    if (t == 0) {
      int g = sm.sel.gsel;
      uint32_t cum = (g < 255) ? sm.sel.part[g + 1] : 0u;
      int d = g * 8;
      for (int e = g * 8 + 7; e >= g * 8; --e) {
        uint32_t he = sm.sel.hist[e];
        if (cum + he >= k) { d = e; break; }
        cum += he;
      }
      sm.sel.skk = k - cum;
      sm.sel.spref = (pref << 11) | (uint64_t)(uint32_t)d;
    }
    __syncthreads();
  }
  // ---- collect survivor indices (ballot-aggregated; exactly 2048, unique keys) ----
  uint64_t thr = sm.sel.spref;
  uint32_t niter = (n + 255u) >> 8;
  for (uint32_t it2 = 0; it2 < niter; ++it2) {
    uint32_t j = it2 * 256u + (uint32_t)t;
    uint64_t key = 0ull;
    bool v = false;
    if (j < n) { key = sm.sel.dense[j]; v = key >= thr; }
    unsigned long long m = __ballot(v);
    uint32_t bs = 0;
    if (lane == 0) bs = atomicAdd(&sm.sel.rank, (uint32_t)__popcll(m));
    bs = (uint32_t)__shfl((int)bs, 0, 64);
    if (v) {
      uint32_t s = bs + (uint32_t)__popcll(m & ((1ull << lane) - 1ull));
      if (s < NSEL)
        idxbuf[(uint32_t)list * NSEL + s] = 0xFFFFFu ^ (uint32_t)(key & 0xFFFFFu);
    }
  }
}

__device__ inline void proj_body(uint32_t pb, int t, SMemU& sm,
    const uint32_t* __restrict__ idxbuf, const float* __restrict__ Wm,
    const float* __restrict__ bfc, const float* __restrict__ d1,
    float* __restrict__ va, float* __restrict__ wa) {
  // ---- G = [W|b]^T [W|b] via shuffle reduction (no atomics) ----
  {
    float4 wr = *(const float4*)(Wm + t * 4);
    float av[5] = { wr.x, wr.y, wr.z, wr.w, bfc[t] };
    int lane = t & 63, wvi = t >> 6;
    #pragma unroll
    for (int p = 0; p < 5; ++p)
      #pragma unroll
      for (int q = p; q < 5; ++q) {
        float g = av[p] * av[q];
        #pragma unroll
        for (int off = 32; off > 0; off >>= 1)
          g += __shfl_xor(g, off, 64);
        if (lane == 0) sm.proj.sGw[wvi][p * 5 + q] = g;
      }
  }
  __syncthreads();
  if (t < 25) {
    int p = t / 5, q = t % 5;
    int pp = p < q ? p : q, qq = p < q ? q : p;
    sm.proj.sG[t] = sm.proj.sGw[0][pp * 5 + qq] + sm.proj.sGw[1][pp * 5 + qq]
                  + sm.proj.sGw[2][pp * 5 + qq] + sm.proj.sGw[3][pp * 5 + qq];
  }
  __syncthreads();
  uint32_t tg = pb * 256u + (uint32_t)t;              // 0..4095
  uint32_t idx = idxbuf[tg] & (NPIX - 1u);
  uint32_t hw = idx & (HW - 1u);
  uint32_t bb = idx >> 18;
  const float* f = d1 + ((size_t)bb << 20) + hw;
  float y[5] = { f[0], f[HW], f[2u * HW], f[3u * HW], 1.0f };
  float z[5]; float n2 = 0.f;
  #pragma unroll
  for (int p = 0; p < 5; ++p) {
    float acc = 0.f;
    #pragma unroll
    for (int q = 0; q < 5; ++q) acc += sm.proj.sG[p * 5 + q] * y[q];
    z[p] = acc; n2 += acc * y[p];                     // = |proj|^2
  }
  n2 = fmaxf(n2, 0.f);
  float inv = 1.0f / fmaxf(sqrtf(n2), 1e-8f);
  uint32_t s5 = tg * 5u;
  #pragma unroll
  for (int p = 0; p < 5; ++p) {
    va[s5 + p] = y[p] * inv;
    wa[s5 + p] = z[p] * inv;
  }
}

// bid in [0,1024): i0 = (bid&31)*128, j0 = (bid>>5)*128
__device__ inline void pair_body(uint32_t bid, int t, SMemU& sm,
    const float* __restrict__ va, const float* __restrict__ wa,
    float* __restrict__ psum, uint32_t* __restrict__ pnnz) {
  int i0 = (int)(bid & 31u) * 128;
  int j0 = (int)(bid >> 5) * 128;
  for (int u = t; u < 640; u += 256) {
    sm.pair.sv[u] = va[i0 * 5 + u];
    sm.pair.sw[u] = wa[j0 * 5 + u];
  }
  __syncthreads();
  int ty = t >> 4, tx = t & 15;
  float rv[8][5], rw[8][5];
  #pragma unroll
  for (int a = 0; a < 8; ++a)
    #pragma unroll
    for (int p = 0; p < 5; ++p) {
      rv[a][p] = sm.pair.sv[(ty * 8 + a) * 5 + p];
      rw[a][p] = sm.pair.sw[(tx * 8 + a) * 5 + p];
    }
  float lsum = 0.f; uint32_t lnz = 0;
  #pragma unroll
  for (int a = 0; a < 8; ++a) {
    int gi = i0 + ty * 8 + a;
    #pragma unroll
    for (int q = 0; q < 8; ++q) {
      int gj = j0 + tx * 8 + q;
      float c = rv[a][0]*rw[q][0] + rv[a][1]*rw[q][1] + rv[a][2]*rw[q][2]
              + rv[a][3]*rw[q][3] + rv[a][4]*rw[q][4];
      float s = c * 10.0f;                     // / TAU
      if (gi != gj) {
        if (((gi ^ gj) & 2048) == 0) {         // same block (pos-pos / neg-neg)
          float m = fmaxf(0.5f - s, 0.f);
          lsum += m * m;
          lnz += (m > 0.f) ? 1u : 0u;
        } else {                               // cross block
          lsum += s * s;
          lnz += (s != 0.f) ? 1u : 0u;
        }
      }
    }
  }
  sm.pair.rs[t] = lsum; sm.pair.rn[t] = lnz;
  __syncthreads();
  for (int off = 128; off > 0; off >>= 1) {
    if (t < off) { sm.pair.rs[t] += sm.pair.rs[t + off]; sm.pair.rn[t] += sm.pair.rn[t + off]; }
    __syncthreads();
  }
  if (t == 0) {
    psum[bid] = sm.pair.rs[0];
    pnnz[bid] = sm.pair.rn[0];
  }
  __syncthreads();                           // guard LDS reuse on repeated calls
}

__device__ inline void final_body(int t, SMemU& sm,
    const float* __restrict__ psum, const uint32_t* __restrict__ pnnz,
    float* __restrict__ out) {
  float s = 0.f; uint32_t nz = 0;
  for (int j = t; j < 1024; j += 256) { s += psum[j]; nz += pnnz[j]; }
  sm.pair.rs[t] = s; sm.pair.rn[t] = nz;
  __syncthreads();
  for (int off = 128; off > 0; off >>= 1) {
    if (t < off) { sm.pair.rs[t] += sm.pair.rs[t + off]; sm.pair.rn[t] += sm.pair.rn[t + off]; }
    __syncthreads();
  }
  if (t == 0) out[0] = sm.pair.rs[0] / (float)sm.pair.rn[0];
}

// =============== fused cooperative kernel (single dispatch, 512 blocks) ======
// __launch_bounds__(256,2): VGPR<=256 -> >=2 blocks/CU by registers; LDS 38KB
// -> 4 blocks/CU; 512 blocks <= 2*256 guaranteed co-resident (big slack vs R9's
// exactly-1024 which was refused).
__global__ __launch_bounds__(256, 2) void k_fused(
    const float* __restrict__ pfegc, const float* __restrict__ ppre,
    const float* __restrict__ gt,
    uint32_t kp0, uint32_t kp1, uint32_t kn0, uint32_t kn1,
    const float* __restrict__ Wm, const float* __restrict__ bfc,
    const float* __restrict__ d1,
    uint64_t* __restrict__ seg, uint32_t* __restrict__ idxbuf,
    float* __restrict__ va, float* __restrict__ wa,
    float* __restrict__ psum, uint32_t* __restrict__ pnnz,
    float* __restrict__ out) {
  cg::grid_group grid = cg::this_grid();
  __shared__ SMemU sm;
  int t = threadIdx.x;
  uint32_t b = blockIdx.x;

  front_body(2u * b,      t, sm, pfegc, ppre, gt, kp0, kp1, kn0, kn1, seg);
  front_body(2u * b + 1u, t, sm, pfegc, ppre, gt, kp0, kp1, kn0, kn1, seg);
  grid.sync();
  if (b < 2) sel_body((int)b, t, sm, seg, idxbuf);
  grid.sync();
  if (b < 16) proj_body(b, t, sm, idxbuf, Wm, bfc, d1, va, wa);
  grid.sync();
  pair_body(b,        t, sm, va, wa, psum, pnnz);
  pair_body(b + 512u, t, sm, va, wa, psum, pnnz);
  grid.sync();
  if (b == 0) final_body(t, sm, psum, pnnz, out);
}

// =============== fallback standalone kernels (proven 5-dispatch path) ========
__global__ __launch_bounds__(256) void k_front(
    const float* __restrict__ pfegc, const float* __restrict__ ppre,
    const float* __restrict__ gt,
    uint32_t kp0, uint32_t kp1, uint32_t kn0, uint32_t kn1,
    uint64_t* __restrict__ seg) {
  __shared__ SMemU sm;
  front_body(blockIdx.x, threadIdx.x, sm, pfegc, ppre, gt, kp0, kp1, kn0, kn1, seg);
}
__global__ __launch_bounds__(256) void k_sel(
    const uint64_t* __restrict__ seg, uint32_t* __restrict__ idxbuf) {
  __shared__ SMemU sm;
  sel_body(blockIdx.x, threadIdx.x, sm, seg, idxbuf);
}
__global__ __launch_bounds__(256) void k_proj(
    const uint32_t* __restrict__ idxbuf, const float* __restrict__ Wm,
    const float* __restrict__ bfc, const float* __restrict__ d1,
    float* __restrict__ va, float* __restrict__ wa) {
  __shared__ SMemU sm;
  proj_body(blockIdx.x, threadIdx.x, sm, idxbuf, Wm, bfc, d1, va, wa);
}
__global__ __launch_bounds__(256) void k_pair(
    const float* __restrict__ va, const float* __restrict__ wa,
    float* __restrict__ psum, uint32_t* __restrict__ pnnz) {
  __shared__ SMemU sm;
  pair_body(blockIdx.x, threadIdx.x, sm, va, wa, psum, pnnz);  // FLAT 1-D bid
}
__global__ __launch_bounds__(256) void k_final(
    const float* __restrict__ psum, const uint32_t* __restrict__ pnnz,
    float* __restrict__ out) {
  __shared__ SMemU sm;
  final_body(threadIdx.x, sm, psum, pnnz, out);
}

extern "C" void kernel_launch(void* const* d_in, const int* in_sizes, int n_in,
                              void* d_out, int out_size, void* d_ws, size_t ws_size,
                              hipStream_t stream) {
  (void)in_sizes; (void)n_in; (void)out_size; (void)ws_size;
  const float* d1    = (const float*)d_in[0];
  const float* pfegc = (const float*)d_in[1];
  const float* ppre  = (const float*)d_in[2];
  const float* gt    = (const float*)d_in[3];
  const float* W     = (const float*)d_in[4];
  const float* bfc   = (const float*)d_in[5];
  float* out = (float*)d_out;

  uint8_t* base = (uint8_t*)d_ws;
  uint64_t* seg    = (uint64_t*)(base + OFF_SEG);
  uint32_t* idxbuf = (uint32_t*)(base + OFF_IDX);
  float*    va     = (float*)(base + OFF_VA);
  float*    wa     = (float*)(base + OFF_WA);
  float*    psum   = (float*)(base + OFF_PSUM);
  uint32_t* pnnz   = (uint32_t*)(base + OFF_PNNZ);

  // jax.random.key(42), partitionable split: kp = tf(0,42,{0,0}), kn = tf(0,42,{0,1})
  uint32_t kp0 = 0u, kp1 = 0u; threefry2x32_(0u, 42u, kp0, kp1);
  uint32_t kn0 = 0u, kn1 = 1u; threefry2x32_(0u, 42u, kn0, kn1);

  void* args[] = {
    (void*)&pfegc, (void*)&ppre, (void*)&gt,
    (void*)&kp0, (void*)&kp1, (void*)&kn0, (void*)&kn1,
    (void*)&W, (void*)&bfc, (void*)&d1,
    (void*)&seg, (void*)&idxbuf, (void*)&va, (void*)&wa,
    (void*)&psum, (void*)&pnnz, (void*)&out
  };
  hipError_t e = hipLaunchCooperativeKernel((const void*)k_fused,
                                            dim3(CGRID), dim3(256),
                                            args, 0, stream);
  if (e != hipSuccess) {
    // fallback: proven 5-dispatch pipeline (identical math; R8 = 126 us)
    k_front<<<NSEG, 256, 0, stream>>>(pfegc, ppre, gt, kp0, kp1, kn0, kn1, seg);
    k_sel<<<2, 256, 0, stream>>>(seg, idxbuf);
    k_proj<<<16, 256, 0, stream>>>(idxbuf, W, bfc, d1, va, wa);
    k_pair<<<1024, 256, 0, stream>>>(va, wa, psum, pnnz);
    k_final<<<1, 256, 0, stream>>>(psum, pnnz, out);
  }
}

// Round 11
// 124.222 us; speedup vs baseline: 2.6308x; 2.6308x over previous
//
#include <hip/hip_runtime.h>
#include <stdint.h>

#define HW       262144u     // 512*512
#define NPIX     1048576u    // 4*HW (pixel index fits in 20 bits)
#define NSEL     2048u       // POS_NUM*B = NEG_NUM*B
#define NSEG     1024u       // one segment per front-block per list
#define SEGCAP   16u         // slots/segment (keep-prob 1/32 -> mean ~2.65; P(seg overflow)~1e-9)
#define DENSECAP 3584u       // LDS gather capacity (mean ~2715, +16 sigma)

// workspace byte offsets (~450 KB total)
#define OFF_SEG     0u        // u64[2][NSEG][SEGCAP] = 256 KB (zero-filled unused slots)
#define OFF_IDX     262144u   // u32[4096] pos then neg
#define OFF_VA      278528u   // f32[4096*5]
#define OFF_WA      360448u   // f32[4096*5]
#define OFF_PSUM    442368u   // f32[1024]
#define OFF_PNNZ    446464u   // u32[1024]

// ---------------- Threefry-2x32-20 (JAX partitionable PRNG) ----------------
#define TF_ROUND(r) { x0 += x1; x1 = (x1 << (r)) | (x1 >> (32 - (r))); x1 ^= x0; }
__host__ __device__ inline void threefry2x32_(uint32_t k0, uint32_t k1,
                                              uint32_t& x0, uint32_t& x1) {
  uint32_t k2 = k0 ^ k1 ^ 0x1BD11BDAu;
  x0 += k0; x1 += k1;
  TF_ROUND(13) TF_ROUND(15) TF_ROUND(26) TF_ROUND(6)
  x0 += k1; x1 += k2 + 1u;
  TF_ROUND(17) TF_ROUND(29) TF_ROUND(16) TF_ROUND(24)
  x0 += k2; x1 += k0 + 2u;
  TF_ROUND(13) TF_ROUND(15) TF_ROUND(26) TF_ROUND(6)
  x0 += k0; x1 += k1 + 3u;
  TF_ROUND(17) TF_ROUND(29) TF_ROUND(16) TF_ROUND(24)
  x0 += k1; x1 += k2 + 4u;
  TF_ROUND(13) TF_ROUND(15) TF_ROUND(26) TF_ROUND(6)
  x0 += k2; x1 += k0 + 5u;
}

// ---------------- front: mask + PRNG + fixed-threshold compaction ----------------
// keep iff top-5 bits of the 23-bit random == 0x1F (keep-prob 1/32). Keep-set is
// upward-closed in key order; E[survivors] ~2715 >= 2048 at ~13 sigma, so the
// exact top-2048 is a subset of the survivors. Unused slots are zeroed (bit43
// marker distinguishes real keys), so the back-end sweeps the array blindly.
__global__ __launch_bounds__(256) void k_front(
    const float* __restrict__ pfegc, const float* __restrict__ ppre,
    const float* __restrict__ gt,
    uint32_t kp0, uint32_t kp1, uint32_t kn0, uint32_t kn1,
    uint64_t* __restrict__ seg) {
  __shared__ uint32_t cnt2[2];
  int t = threadIdx.x;
  uint32_t b = blockIdx.x;
  if (t < 2) cnt2[t] = 0;
  if (t < 2 * (int)SEGCAP) {                // zero-fill this block's two segments
    uint32_t list = (uint32_t)t / SEGCAP, slot = (uint32_t)t % SEGCAP;
    seg[((size_t)list * NSEG + b) * SEGCAP + slot] = 0ull;
  }
  __syncthreads();
  uint32_t base = b * 1024u + (uint32_t)t * 4u;
  float4 pf = *(const float4*)(pfegc + base);
  float pfa[4] = { pf.x, pf.y, pf.z, pf.w };
  bool any = (pf.x >= 0.5f) || (pf.y >= 0.5f) || (pf.z >= 0.5f) || (pf.w >= 0.5f);
  if (any) {
    uint32_t hw = base & (HW - 1u);
    uint32_t bb = base >> 18;                 // base..base+3 share the image
    const float* pp = ppre + (size_t)bb * 3u * HW + hw;
    float4 p0 = *(const float4*)pp;
    float4 p1 = *(const float4*)(pp + HW);
    float4 p2 = *(const float4*)(pp + 2u * HW);
    float4 g4 = *(const float4*)(gt + base);
    float p0a[4] = { p0.x, p0.y, p0.z, p0.w };
    float p1a[4] = { p1.x, p1.y, p1.z, p1.w };
    float p2a[4] = { p2.x, p2.y, p2.z, p2.w };
    float ga[4]  = { g4.x, g4.y, g4.z, g4.w };
    #pragma unroll
    for (int j = 0; j < 4; ++j) {
      if (pfa[j] >= 0.5f && p0a[j] >= p1a[j] && p0a[j] >= p2a[j]) {
        uint32_t i = base + (uint32_t)j;
        bool gfg = ga[j] > 0.5f;
        uint32_t x0 = 0u, x1 = i;
        threefry2x32_(gfg ? kp0 : kn0, gfg ? kp1 : kn1, x0, x1);
        uint32_t r23 = (x0 ^ x1) >> 9;
        if ((r23 >> 18) == 0x1Fu) {           // fixed prefilter, keep-prob 1/32
          uint32_t list = gfg ? 0u : 1u;
          uint32_t r = atomicAdd(&cnt2[list], 1u);     // u32 LDS atomic, rare
          if (r < SEGCAP)
            seg[((size_t)list * NSEG + b) * SEGCAP + r] =
                (1ull << 43) | ((uint64_t)r23 << 20) | (uint64_t)(0xFFFFFu ^ i);
        }
      }
    }
  }
}

// ---------------- select exact top-2048 (1 block/list) ----------------
// count -> scan -> scatter sweep; 16B vector loads (global_load_dwordx4).
// Then 4-round 11-bit radix select; survivors -> idxbuf.
__global__ __launch_bounds__(256) void k_sel(
    const uint64_t* __restrict__ seg, uint32_t* __restrict__ idxbuf) {
  __shared__ uint64_t dense[DENSECAP];   // 28 KB
  __shared__ uint32_t hist[2048];        // 8 KB
  __shared__ uint32_t part[256];
  __shared__ uint32_t skk, rank, ntot;
  __shared__ int gsel;
  __shared__ uint64_t spref;
  int t = threadIdx.x;
  int list = blockIdx.x;
  uint32_t lane = (uint32_t)t & 63u;
  if (t == 0) { spref = 0ull; skk = NSEL; rank = 0; }
  const uint4* sp4 = (const uint4*)(seg + (size_t)list * NSEG * SEGCAP);
  // ---- Phase A: count valid keys (bit43 marker); 16B coalesced loads ----
  uint32_t c = 0;
  #pragma unroll
  for (int it = 0; it < 32; ++it) {
    uint4 v = sp4[(uint32_t)it * 256u + (uint32_t)t];
    c += ((v.y >> 11) & 1u) + ((v.w >> 11) & 1u);   // bit43 = bit11 of high word
  }
  part[t] = c;
  __syncthreads();
  for (int off = 1; off < 256; off <<= 1) {
    uint32_t x = part[t];
    uint32_t add = (t >= off) ? part[t - off] : 0u;
    __syncthreads();
    part[t] = x + add;
    __syncthreads();
  }
  uint32_t wbase = part[t] - c;          // exclusive prefix = this thread's base
  if (t == 255) ntot = part[255];
  // ---- Phase B: re-load (L2-hot) and scatter to dense ----
  #pragma unroll
  for (int it = 0; it < 32; ++it) {
    uint4 v = sp4[(uint32_t)it * 256u + (uint32_t)t];
    uint64_t k0 = ((uint64_t)v.y << 32) | v.x;
    uint64_t k1 = ((uint64_t)v.w << 32) | v.z;
    if (k0 >> 43) { if (wbase < DENSECAP) dense[wbase] = k0; ++wbase; }
    if (k1 >> 43) { if (wbase < DENSECAP) dense[wbase] = k1; ++wbase; }
  }
  __syncthreads();
  uint32_t n = ntot; if (n > DENSECAP) n = DENSECAP;
  // ---- 4-round 11-bit radix select of the exact 2048th-largest key ----
  for (int r = 0; r < 4; ++r) {
    #pragma unroll
    for (int e = 0; e < 8; ++e) hist[t * 8 + e] = 0;
    __syncthreads();
    int csp = 44 - 11 * r;
    int cs = csp - 11;
    uint64_t pref = spref;
    for (uint32_t j = t; j < n; j += 256) {
      uint64_t key = dense[j];
      if ((key >> csp) == pref)
        atomicAdd(&hist[(uint32_t)(key >> cs) & 0x7FFu], 1u);
    }
    __syncthreads();
    uint32_t ss = 0;
    #pragma unroll
    for (int e = 0; e < 8; ++e) ss += hist[t * 8 + e];
    part[t] = ss;
    __syncthreads();
    for (int off = 1; off < 256; off <<= 1) {
      uint32_t x = part[t];
      uint32_t y = (t + off < 256) ? part[t + off] : 0u;
      __syncthreads();
      part[t] = x + y;
      __syncthreads();
    }
    uint32_t k = skk;
    if (part[t] >= k && (t == 255 || part[t + 1] < k)) gsel = t;
    __syncthreads();
    if (t == 0) {
      int g = gsel;
      uint32_t cum = (g < 255) ? part[g + 1] : 0u;
      int d = g * 8;
      for (int e = g * 8 + 7; e >= g * 8; --e) {
        uint32_t he = hist[e];
        if (cum + he >= k) { d = e; break; }
        cum += he;
      }
      skk = k - cum;
      spref = (pref << 11) | (uint64_t)(uint32_t)d;
    }
    __syncthreads();
  }
  // ---- collect survivor indices (ballot-aggregated; exactly 2048, unique keys) ----
  uint64_t thr = spref;
  uint32_t niter = (n + 255u) >> 8;
  for (uint32_t it2 = 0; it2 < niter; ++it2) {
    uint32_t j = it2 * 256u + (uint32_t)t;
    uint64_t key = 0ull;
    bool v = false;
    if (j < n) { key = dense[j]; v = key >= thr; }
    unsigned long long m = __ballot(v);
    uint32_t bs = 0;
    if (lane == 0) bs = atomicAdd(&rank, (uint32_t)__popcll(m));
    bs = (uint32_t)__shfl((int)bs, 0, 64);
    if (v) {
      uint32_t s = bs + (uint32_t)__popcll(m & ((1ull << lane) - 1ull));
      if (s < NSEL)
        idxbuf[(uint32_t)list * NSEL + s] = 0xFFFFFu ^ (uint32_t)(key & 0xFFFFFu);
    }
  }
}

// ---------------- project: v = y/|proj|, w = G v (1 point/thread, 16 blocks) ----------------
__global__ __launch_bounds__(256) void k_proj(
    const uint32_t* __restrict__ idxbuf, const float* __restrict__ Wm,
    const float* __restrict__ bfc, const float* __restrict__ d1,
    float* __restrict__ va, float* __restrict__ wa) {
  __shared__ float sG[25];
  __shared__ float sGw[4][25];
  int t = threadIdx.x;
  // ---- G = [W|b]^T [W|b] via shuffle reduction (no atomics) ----
  {
    float4 wr = *(const float4*)(Wm + t * 4);
    float av[5] = { wr.x, wr.y, wr.z, wr.w, bfc[t] };
    int lane = t & 63, wvi = t >> 6;
    #pragma unroll
    for (int p = 0; p < 5; ++p)
      #pragma unroll
      for (int q = p; q < 5; ++q) {
        float g = av[p] * av[q];
        #pragma unroll
        for (int off = 32; off > 0; off >>= 1)
          g += __shfl_xor(g, off, 64);
        if (lane == 0) sGw[wvi][p * 5 + q] = g;
      }
  }
  __syncthreads();
  if (t < 25) {
    int p = t / 5, q = t % 5;
    int pp = p < q ? p : q, qq = p < q ? q : p;
    sG[t] = sGw[0][pp * 5 + qq] + sGw[1][pp * 5 + qq]
          + sGw[2][pp * 5 + qq] + sGw[3][pp * 5 + qq];
  }
  __syncthreads();
  uint32_t tg = blockIdx.x * 256u + (uint32_t)t;      // 0..4095
  uint32_t idx = idxbuf[tg] & (NPIX - 1u);
  uint32_t hw = idx & (HW - 1u);
  uint32_t bb = idx >> 18;
  const float* f = d1 + ((size_t)bb << 20) + hw;
  float y[5] = { f[0], f[HW], f[2u * HW], f[3u * HW], 1.0f };
  float z[5]; float n2 = 0.f;
  #pragma unroll
  for (int p = 0; p < 5; ++p) {
    float acc = 0.f;
    #pragma unroll
    for (int q = 0; q < 5; ++q) acc += sG[p * 5 + q] * y[q];
    z[p] = acc; n2 += acc * y[p];                     // = |proj|^2
  }
  n2 = fmaxf(n2, 0.f);
  float inv = 1.0f / fmaxf(sqrtf(n2), 1e-8f);
  uint32_t s5 = tg * 5u;
  #pragma unroll
  for (int p = 0; p < 5; ++p) {
    va[s5 + p] = y[p] * inv;
    wa[s5 + p] = z[p] * inv;
  }
}

// ---------------- pairwise loss: per-block partials, plain stores ----------------
__global__ __launch_bounds__(256) void k_pair(
    const float* __restrict__ va, const float* __restrict__ wa,
    float* __restrict__ psum, uint32_t* __restrict__ pnnz) {
  __shared__ float sv[128 * 5], sw[128 * 5];
  __shared__ float rs[256];
  __shared__ uint32_t rn[256];
  int i0 = blockIdx.x * 128, j0 = blockIdx.y * 128;
  int t = threadIdx.x;
  for (int u = t; u < 640; u += 256) { sv[u] = va[i0 * 5 + u]; sw[u] = wa[j0 * 5 + u]; }
  __syncthreads();
  int ty = t >> 4, tx = t & 15;
  float rv[8][5], rw[8][5];
  #pragma unroll
  for (int a = 0; a < 8; ++a)
    #pragma unroll
    for (int p = 0; p < 5; ++p) {
      rv[a][p] = sv[(ty * 8 + a) * 5 + p];
      rw[a][p] = sw[(tx * 8 + a) * 5 + p];
    }
  float lsum = 0.f; uint32_t lnz = 0;
  #pragma unroll
  for (int a = 0; a < 8; ++a) {
    int gi = i0 + ty * 8 + a;
    #pragma unroll
    for (int q = 0; q < 8; ++q) {
      int gj = j0 + tx * 8 + q;
      float c = rv[a][0]*rw[q][0] + rv[a][1]*rw[q][1] + rv[a][2]*rw[q][2]
              + rv[a][3]*rw[q][3] + rv[a][4]*rw[q][4];
      float s = c * 10.0f;                     // / TAU
      if (gi != gj) {
        if (((gi ^ gj) & 2048) == 0) {         // same block (pos-pos / neg-neg)
          float m = fmaxf(0.5f - s, 0.f);
          lsum += m * m;
          lnz += (m > 0.f) ? 1u : 0u;
        } else {                               // cross block
          lsum += s * s;
          lnz += (s != 0.f) ? 1u : 0u;
        }
      }
    }
  }
  rs[t] = lsum; rn[t] = lnz;
  __syncthreads();
  for (int off = 128; off > 0; off >>= 1) {
    if (t < off) { rs[t] += rs[t + off]; rn[t] += rn[t + off]; }
    __syncthreads();
  }
  if (t == 0) {
    int bid = blockIdx.y * gridDim.x + blockIdx.x;
    psum[bid] = rs[0];
    pnnz[bid] = rn[0];
  }
}

__global__ __launch_bounds__(256) void k_final(const float* __restrict__ psum,
                                               const uint32_t* __restrict__ pnnz,
                                               float* __restrict__ out) {
  __shared__ float rs[256];
  __shared__ uint32_t rn[256];
  int t = threadIdx.x;
  float s = 0.f; uint32_t nz = 0;
  for (int j = t; j < 1024; j += 256) { s += psum[j]; nz += pnnz[j]; }
  rs[t] = s; rn[t] = nz;
  __syncthreads();
  for (int off = 128; off > 0; off >>= 1) {
    if (t < off) { rs[t] += rs[t + off]; rn[t] += rn[t + off]; }
    __syncthreads();
  }
  if (t == 0) out[0] = rs[0] / (float)rn[0];
}

extern "C" void kernel_launch(void* const* d_in, const int* in_sizes, int n_in,
                              void* d_out, int out_size, void* d_ws, size_t ws_size,
                              hipStream_t stream) {
  (void)in_sizes; (void)n_in; (void)out_size; (void)ws_size;
  const float* d1    = (const float*)d_in[0];
  const float* pfegc = (const float*)d_in[1];
  const float* ppre  = (const float*)d_in[2];
  const float* gt    = (const float*)d_in[3];
  const float* W     = (const float*)d_in[4];
  const float* bfc   = (const float*)d_in[5];
  float* out = (float*)d_out;

  uint8_t* base = (uint8_t*)d_ws;
  uint64_t* seg    = (uint64_t*)(base + OFF_SEG);
  uint32_t* idxbuf = (uint32_t*)(base + OFF_IDX);
  float*    va     = (float*)(base + OFF_VA);
  float*    wa     = (float*)(base + OFF_WA);
  float*    psum   = (float*)(base + OFF_PSUM);
  uint32_t* pnnz   = (uint32_t*)(base + OFF_PNNZ);

  // jax.random.key(42), partitionable split: kp = tf(0,42,{0,0}), kn = tf(0,42,{0,1})
  uint32_t kp0 = 0u, kp1 = 0u; threefry2x32_(0u, 42u, kp0, kp1);
  uint32_t kn0 = 0u, kn1 = 1u; threefry2x32_(0u, 42u, kn0, kn1);

  k_front<<<NSEG, 256, 0, stream>>>(pfegc, ppre, gt, kp0, kp1, kn0, kn1, seg);
  k_sel<<<2, 256, 0, stream>>>(seg, idxbuf);
  k_proj<<<16, 256, 0, stream>>>(idxbuf, W, bfc, d1, va, wa);
  k_pair<<<dim3(32, 32), 256, 0, stream>>>(va, wa, psum, pnnz);
  k_final<<<1, 256, 0, stream>>>(psum, pnnz, out);
}